// Round 15
// baseline (240.585 us; speedup 1.0000x reference)
//
#include <hip/hip_runtime.h>
#include <hip/hip_bf16.h>
#include <hip/hip_fp16.h>
#include <hip/hip_cooperative_groups.h>

namespace cg = cooperative_groups;

// GCN 2-layer: h1 = relu(Ahat (x@W1) + b1); out = softmax(relu(Ahat (h1@W2) + b2))
// Ahat = D^-1/2 (A + I) D^-1/2.
// dinv[src] folded into GEMM epilogues (h' = dinv*h, fp16); aggregation is a
// register gather + shfl reduce over interleaved 96B fp16 rows (round-11
// structure, 47.6us = ~90% of the 2.6TB/s random-fetch ceiling; fetch-bound,
// rate invariant across VALUBusy 29-57%).
// Rejected by measurement: LDS-atomic scatter (10x), L2-chunking (4.7x),
// global-atomic deg (8x), fixed-8 unroll (1.6x), 128B-pad+fused-gemm2 (1.5x).
// CSR build: single cooperative kernel (5 kernels + 4 launch gaps fused),
// bucketed counting sort, LDS counting, int4-vectorized streams.

#define TILE 8192  // edges per histogram/scatter tile (196 blocks, co-resident)

typedef _Float16 half8 __attribute__((ext_vector_type(8)));
typedef float floatx4 __attribute__((ext_vector_type(4)));

// ---- fused CSR build (cooperative, one launch) ----
// phase1 hist -> sync -> phase2 bucket sums -> sync -> phase3 prefix+offsets
// -> sync -> phase4 scatter -> sync -> phase5 csrfill (grid-strided buckets)
__global__ __launch_bounds__(256) void k_build(const int* __restrict__ ei, int E,
                                               int* __restrict__ Hw, int nbuck,
                                               int nTiles, int* __restrict__ btot,
                                               int* __restrict__ bstart,
                                               int* __restrict__ ebuf,
                                               int* __restrict__ csr,
                                               int* __restrict__ rowstart,
                                               float* __restrict__ dinv, int N) {
    cg::grid_group grid = cg::this_grid();
    __shared__ int h[512];      // hist / scatter cursors
    __shared__ int lcnt[256];   // csrfill counts
    __shared__ int lscan[256];
    __shared__ int lcur[256];
    int t = threadIdx.x;
    const int* dst = ei + E;
    bool isTile = (int)blockIdx.x < nTiles;

    // --- phase 1: per-tile bucket histogram (int4 loads) ---
    if (isTile) {
        for (int i = t; i < nbuck; i += 256) h[i] = 0;
        __syncthreads();
        int base = blockIdx.x * TILE;
#pragma unroll
        for (int r = 0; r < TILE / 1024; ++r) {
            int e = base + (r * 256 + t) * 4;
            if (e + 3 < E) {
                int4 d4 = *(const int4*)(dst + e);
                atomicAdd(&h[d4.x >> 8], 1);
                atomicAdd(&h[d4.y >> 8], 1);
                atomicAdd(&h[d4.z >> 8], 1);
                atomicAdd(&h[d4.w >> 8], 1);
            } else {
                for (int k = 0; k < 4; ++k)
                    if (e + k < E) atomicAdd(&h[dst[e + k] >> 8], 1);
            }
        }
        __syncthreads();
        for (int i = t; i < nbuck; i += 256) Hw[blockIdx.x * nbuck + i] = h[i];
    }
    grid.sync();

    // --- phase 2: bucket totals (wave per bucket, grid-stride) ---
    int gw = (blockIdx.x * 256 + t) >> 6;
    int lane = t & 63;
    int nw = (gridDim.x * 256) >> 6;
    for (int wid = gw; wid < nbuck; wid += nw) {
        int sum = 0;
        for (int tt = lane; tt < nTiles; tt += 64) sum += Hw[tt * nbuck + wid];
#pragma unroll
        for (int off = 32; off; off >>= 1) sum += __shfl_down(sum, off);
        if (lane == 0) btot[wid] = sum;
    }
    grid.sync();

    // --- phase 3: per-bucket prefix (from btot) + per-(tile,bucket) offsets ---
    for (int wid = gw; wid < nbuck; wid += nw) {
        int ps = 0;
        for (int j = lane; j < wid; j += 64) ps += btot[j];
#pragma unroll
        for (int off = 32; off; off >>= 1) ps += __shfl_down(ps, off);
        int prefix = __shfl(ps, 0);
        if (lane == 0) {
            bstart[wid] = prefix;
            if (wid == nbuck - 1) bstart[nbuck] = prefix + btot[wid];
        }
        int running = prefix;
        for (int chunk = 0; chunk < nTiles; chunk += 64) {
            int tt = chunk + lane;
            int v = (tt < nTiles) ? Hw[tt * nbuck + wid] : 0;
            int incl = v;
#pragma unroll
            for (int off = 1; off < 64; off <<= 1) {
                int u = __shfl_up(incl, off);
                if (lane >= off) incl += u;
            }
            if (tt < nTiles) Hw[tt * nbuck + wid] = running + (incl - v);
            running += __shfl(incl, 63);
        }
    }
    grid.sync();

    // --- phase 4: scatter edges bucket-grouped (int4 loads) ---
    if (isTile) {
        for (int i = t; i < nbuck; i += 256) h[i] = Hw[blockIdx.x * nbuck + i];
        __syncthreads();
        int base = blockIdx.x * TILE;
        bool al = (E & 3) == 0;
#pragma unroll
        for (int r = 0; r < TILE / 1024; ++r) {
            int e = base + (r * 256 + t) * 4;
            if (al && e + 3 < E) {
                int4 s4 = *(const int4*)(ei + e);
                int4 d4 = *(const int4*)(ei + E + e);
                int p0 = atomicAdd(&h[d4.x >> 8], 1);
                ebuf[p0] = s4.x | ((d4.x & 255) << 17);
                int p1 = atomicAdd(&h[d4.y >> 8], 1);
                ebuf[p1] = s4.y | ((d4.y & 255) << 17);
                int p2 = atomicAdd(&h[d4.z >> 8], 1);
                ebuf[p2] = s4.z | ((d4.z & 255) << 17);
                int p3 = atomicAdd(&h[d4.w >> 8], 1);
                ebuf[p3] = s4.w | ((d4.w & 255) << 17);
            } else {
                for (int k = 0; k < 4; ++k) {
                    int ek = e + k;
                    if (ek < E) {
                        int s = ei[ek];
                        int d = ei[E + ek];
                        int pos = atomicAdd(&h[d >> 8], 1);
                        ebuf[pos] = s | ((d & 255) << 17);
                    }
                }
            }
        }
    }
    grid.sync();

    // --- phase 5: csrfill (bucket per block, grid-strided) ---
    for (int b = blockIdx.x; b < nbuck; b += gridDim.x) {
        int nodebase = b << 8;
        int segs = bstart[b];
        int sege = bstart[b + 1];
        int vstart = (segs + 3) & ~3;
        if (vstart > sege) vstart = sege;
        int vend = sege & ~3;
        if (vend < vstart) vend = vstart;
        lcnt[t] = 0;
        __syncthreads();
        for (int i = segs + t; i < vstart; i += 256)
            atomicAdd(&lcnt[((unsigned)ebuf[i]) >> 17], 1);
        for (int i = vstart + t * 4; i < vend; i += 1024) {
            int4 p4 = *(const int4*)(ebuf + i);
            atomicAdd(&lcnt[((unsigned)p4.x) >> 17], 1);
            atomicAdd(&lcnt[((unsigned)p4.y) >> 17], 1);
            atomicAdd(&lcnt[((unsigned)p4.z) >> 17], 1);
            atomicAdd(&lcnt[((unsigned)p4.w) >> 17], 1);
        }
        for (int i = vend + t; i < sege; i += 256)
            atomicAdd(&lcnt[((unsigned)ebuf[i]) >> 17], 1);
        __syncthreads();
        int v = lcnt[t];
        lscan[t] = v;
        __syncthreads();
        for (int off = 1; off < 256; off <<= 1) {
            int tmp = (t >= off) ? lscan[t - off] : 0;
            __syncthreads();
            lscan[t] += tmp;
            __syncthreads();
        }
        int excl = lscan[t] - v;
        int node = nodebase + t;
        int rs = segs + excl;
        if (node < N) {
            rowstart[node] = rs;
            dinv[node] = rsqrtf((float)(v + 1));  // +1 self loop
            if (node == N - 1) rowstart[N] = rs + v;  // sentinel
        }
        lcur[t] = rs;
        __syncthreads();
        for (int i = segs + t; i < vstart; i += 256) {
            int pk = ebuf[i];
            int pos = atomicAdd(&lcur[((unsigned)pk) >> 17], 1);
            csr[pos] = pk & 0x1FFFF;
        }
        for (int i = vstart + t * 4; i < vend; i += 1024) {
            int4 p4 = *(const int4*)(ebuf + i);
            int pos0 = atomicAdd(&lcur[((unsigned)p4.x) >> 17], 1);
            csr[pos0] = p4.x & 0x1FFFF;
            int pos1 = atomicAdd(&lcur[((unsigned)p4.y) >> 17], 1);
            csr[pos1] = p4.y & 0x1FFFF;
            int pos2 = atomicAdd(&lcur[((unsigned)p4.z) >> 17], 1);
            csr[pos2] = p4.z & 0x1FFFF;
            int pos3 = atomicAdd(&lcur[((unsigned)p4.w) >> 17], 1);
            csr[pos3] = p4.w & 0x1FFFF;
        }
        for (int i = vend + t; i < sege; i += 256) {
            int pk = ebuf[i];
            int pos = atomicAdd(&lcur[((unsigned)pk) >> 17], 1);
            csr[pos] = pk & 0x1FFFF;
        }
        __syncthreads();  // before next bucket iteration reuses lcnt
    }
}

// h1p[N][48] = fp16( dinv[r] * (x[N][128] @ W1[128][48]) ) via MFMA 16x16x32 f16.
__global__ __launch_bounds__(256) void k_gemm1(const float* __restrict__ x,
                                               const float* __restrict__ W1,
                                               const float* __restrict__ dinv,
                                               __half* __restrict__ h1p, int N) {
    __shared__ _Float16 wt[48 * 136];
    int t = threadIdx.x;
    for (int i = t; i < 128 * 48; i += 256) {
        int k = i / 48, c = i % 48;
        wt[c * 136 + k] = (_Float16)W1[i];
    }
    __syncthreads();

    int wave = t >> 6, lane = t & 63;
    int g = lane >> 4;
    int rtile = blockIdx.x * 64 + wave * 16;
    int rowA = rtile + (lane & 15);
    const float* xrow = x + (size_t)(rowA < N ? rowA : N - 1) * 128;
    int c0 = lane & 15;

    floatx4 acc[3];
#pragma unroll
    for (int nt = 0; nt < 3; ++nt)
#pragma unroll
        for (int q = 0; q < 4; ++q) acc[nt][q] = 0.f;

#pragma unroll
    for (int kc = 0; kc < 4; ++kc) {
        int k0 = kc * 32 + g * 8;
        float4 a0 = *(const float4*)(xrow + k0);
        float4 a1 = *(const float4*)(xrow + k0 + 4);
        half8 a;
        a[0] = (_Float16)a0.x; a[1] = (_Float16)a0.y;
        a[2] = (_Float16)a0.z; a[3] = (_Float16)a0.w;
        a[4] = (_Float16)a1.x; a[5] = (_Float16)a1.y;
        a[6] = (_Float16)a1.z; a[7] = (_Float16)a1.w;
#pragma unroll
        for (int nt = 0; nt < 3; ++nt) {
            half8 b = *(const half8*)(&wt[(nt * 16 + c0) * 136 + k0]);
            acc[nt] = __builtin_amdgcn_mfma_f32_16x16x32_f16(a, b, acc[nt], 0, 0, 0);
        }
    }

    int rbase = rtile + g * 4;
#pragma unroll
    for (int j = 0; j < 4; ++j) {
        int r = rbase + j;
        if (r < N) {
            float dr = dinv[r];
#pragma unroll
            for (int nt = 0; nt < 3; ++nt)
                h1p[(size_t)r * 48 + nt * 16 + c0] = __float2half(acc[nt][j] * dr);
        }
    }
}

// layer-1 aggregation (round-11 structure, best measured): wave per node;
// 8 edge-groups x (6 lanes x float4) over 96B rows; degree-adaptive loop;
// shfl-xor fold; epilogue self + bias + relu, writes r1 fp16.
__global__ __launch_bounds__(256) void k_agg1(const __half* __restrict__ h1p,
                                              const int* __restrict__ csr,
                                              const int* __restrict__ rowstart,
                                              const float* __restrict__ dinv,
                                              const float* __restrict__ b1,
                                              __half* __restrict__ r1h, int N) {
    int wave = threadIdx.x >> 6;
    int lane = threadIdx.x & 63;
    int v = blockIdx.x * 4 + wave;
    if (v >= N) return;
    int grp = lane >> 3;  // edge group 0..7
    int sub = lane & 7;   // subs 0..5 carry features sub*8..sub*8+7

    int start = rowstart[v];
    int d = rowstart[v + 1] - start;
    float dv = dinv[v];
    const int* cs = csr + start;
    const char* h1b = (const char*)h1p;

    float acc[8] = {0.f, 0.f, 0.f, 0.f, 0.f, 0.f, 0.f, 0.f};

    for (int base = 0; base < d; base += 64) {
        int sreg = (base + lane < d) ? cs[base + lane] : 0;
        int nb = min(64, d - base);
        for (int j = 0; j < 8 && j * 8 < nb; ++j) {
            int s = __shfl(sreg, j * 8 + grp);
            if (j * 8 + grp < nb && sub < 6) {
                float4 rv = *(const float4*)(h1b + (size_t)s * 96 + sub * 16);
                const __half2* hp = (const __half2*)&rv;
#pragma unroll
                for (int q = 0; q < 4; ++q) {
                    float2 f = __half22float2(hp[q]);
                    acc[q * 2] += f.x;
                    acc[q * 2 + 1] += f.y;
                }
            }
        }
    }
    // fold the 8 edge groups (idle sub-lanes hold zeros)
#pragma unroll
    for (int i = 0; i < 8; ++i) {
        acc[i] += __shfl_xor(acc[i], 8);
        acc[i] += __shfl_xor(acc[i], 16);
        acc[i] += __shfl_xor(acc[i], 32);
    }
    if (grp == 0 && sub < 6) {
        float4 sv = *(const float4*)(h1b + (size_t)v * 96 + sub * 16);
        const __half2* hp = (const __half2*)&sv;
        __half2 ob[4];
#pragma unroll
        for (int q = 0; q < 4; ++q) {
            float2 sf = __half22float2(hp[q]);
            int fi = sub * 8 + q * 2;
            float o0 = fmaxf(dv * (acc[q * 2] + sf.x) + b1[fi], 0.f);
            float o1 = fmaxf(dv * (acc[q * 2 + 1] + sf.y) + b1[fi + 1], 0.f);
            ob[q] = __floats2half2_rn(o0, o1);
        }
        *(float4*)((char*)r1h + (size_t)v * 96 + sub * 16) = *(const float4*)ob;
    }
}

// h2p[N][16] = fp16( dinv[row] * (r1h[N][48] @ W2[48][16]) ), r1h fp16
__global__ __launch_bounds__(256) void k_gemm2(const __half* __restrict__ r1h,
                                               const float* __restrict__ W2,
                                               const float* __restrict__ dinv,
                                               __half* __restrict__ h2p, int N) {
    __shared__ float w2s[48 * 16];
    int t = threadIdx.x;
    for (int i = t; i < 768; i += 256) w2s[i] = W2[i];
    __syncthreads();
    int flat = blockIdx.x * 256 + t;
    int row = flat >> 2;
    int cg = (flat & 3) * 4;
    if (row >= N) return;
    float4 acc = make_float4(0.f, 0.f, 0.f, 0.f);
    const __half2* xr = (const __half2*)((const char*)r1h + (size_t)row * 96);
#pragma unroll 4
    for (int kk = 0; kk < 24; ++kk) {
        float2 a = __half22float2(xr[kk]);
        float4 b0 = *(const float4*)(w2s + (2 * kk) * 16 + cg);
        float4 b1v = *(const float4*)(w2s + (2 * kk + 1) * 16 + cg);
        acc.x += a.x * b0.x + a.y * b1v.x;
        acc.y += a.x * b0.y + a.y * b1v.y;
        acc.z += a.x * b0.z + a.y * b1v.z;
        acc.w += a.x * b0.w + a.y * b1v.w;
    }
    float dr = dinv[row];
    __half2 h01 = __floats2half2_rn(acc.x * dr, acc.y * dr);
    __half2 h23 = __floats2half2_rn(acc.z * dr, acc.w * dr);
    __half* dst = h2p + (size_t)row * 16 + cg;
    *(__half2*)(dst) = h01;
    *(__half2*)(dst + 2) = h23;
}

// layer-2 aggregation: 2 nodes/wave; per half-wave 16 edge-groups x
// (2 lanes x float4) = 16 edges per load instruction. Softmax in sub-lanes.
__global__ __launch_bounds__(256) void k_agg2(const __half* __restrict__ h2p,
                                              const int* __restrict__ csr,
                                              const int* __restrict__ rowstart,
                                              const float* __restrict__ dinv,
                                              const float* __restrict__ b2,
                                              float* __restrict__ out, int N) {
    int tid = threadIdx.x;
    int lane = tid & 63;
    int hf = lane >> 5;
    int l32 = lane & 31;
    int grp = l32 >> 1;
    int sub = lane & 1;
    int v = (blockIdx.x * 4 + (tid >> 6)) * 2 + hf;
    if (v >= N) return;

    int start = rowstart[v];
    int d = rowstart[v + 1] - start;
    float dv = dinv[v];
    const int* cs = csr + start;
    const char* h2b = (const char*)h2p;

    float acc[8] = {0.f, 0.f, 0.f, 0.f, 0.f, 0.f, 0.f, 0.f};

    for (int base = 0; base < d; base += 32) {
        int sreg = (base + l32 < d) ? cs[base + l32] : 0;
        int nb = min(32, d - base);
        for (int j = 0; j < 2 && j * 16 < nb; ++j) {
            int e = j * 16 + grp;
            int s = __shfl(sreg, (hf << 5) + e);
            if (e < nb) {
                float4 rv = *(const float4*)(h2b + (size_t)s * 32 + sub * 16);
                const __half2* hp = (const __half2*)&rv;
#pragma unroll
                for (int q = 0; q < 4; ++q) {
                    float2 f = __half22float2(hp[q]);
                    acc[q * 2] += f.x;
                    acc[q * 2 + 1] += f.y;
                }
            }
        }
    }
#pragma unroll
    for (int i = 0; i < 8; ++i) {
        acc[i] += __shfl_xor(acc[i], 2);
        acc[i] += __shfl_xor(acc[i], 4);
        acc[i] += __shfl_xor(acc[i], 8);
        acc[i] += __shfl_xor(acc[i], 16);
    }
    if (grp == 0) {
        float4 sv = *(const float4*)(h2b + (size_t)v * 32 + sub * 16);
        const __half2* hp = (const __half2*)&sv;
        float z[8];
#pragma unroll
        for (int q = 0; q < 4; ++q) {
            float2 f = __half22float2(hp[q]);
            z[q * 2]     = fmaxf(dv * (acc[q * 2] + f.x) + b2[sub * 8 + q * 2], 0.f);
            z[q * 2 + 1] = fmaxf(dv * (acc[q * 2 + 1] + f.y) + b2[sub * 8 + q * 2 + 1], 0.f);
        }
        float m8 = z[0];
#pragma unroll
        for (int i = 1; i < 8; ++i) m8 = fmaxf(m8, z[i]);
        float m = fmaxf(m8, __shfl_xor(m8, 1));
        float p[8];
        float s8 = 0.f;
#pragma unroll
        for (int i = 0; i < 8; ++i) { p[i] = __expf(z[i] - m); s8 += p[i]; }
        float inv = 1.f / (s8 + __shfl_xor(s8, 1));
        float4* dst = (float4*)(out + (size_t)v * 16 + sub * 8);
        dst[0] = make_float4(p[0] * inv, p[1] * inv, p[2] * inv, p[3] * inv);
        dst[1] = make_float4(p[4] * inv, p[5] * inv, p[6] * inv, p[7] * inv);
    }
}

extern "C" void kernel_launch(void* const* d_in, const int* in_sizes, int n_in,
                              void* d_out, int out_size, void* d_ws, size_t ws_size,
                              hipStream_t stream) {
    const int*   ei_c = (const int*)d_in[1];
    const float* x  = (const float*)d_in[0];
    const float* W1 = (const float*)d_in[2];
    const float* b1 = (const float*)d_in[3];
    const float* W2 = (const float*)d_in[4];
    const float* b2 = (const float*)d_in[5];
    float* out = (float*)d_out;

    int N = in_sizes[0] / 128;
    int E = in_sizes[1] / 2;
    int NBK = (N + 255) >> 8;
    int nTiles = (E + TILE - 1) / TILE;

    char* p = (char*)d_ws;
    auto alloc = [&](size_t bytes) -> char* {
        char* q = p;
        p += (bytes + 255) & ~(size_t)255;
        return q;
    };
    int*    rowstart = (int*)alloc((size_t)(N + 1) * 4);   // +1 sentinel
    float*  dinv     = (float*)alloc((size_t)N * 4);
    int*    btot     = (int*)alloc((size_t)NBK * 4);
    int*    bstart   = (int*)alloc((size_t)(NBK + 1) * 4);
    int*    Hw       = (int*)alloc((size_t)nTiles * NBK * 4);
    int*    csr      = (int*)alloc((size_t)E * 4);
    // ebuf (E*4) dead after k_build; h1p (N*48*2) overlays it; h2p after agg1.
    size_t  ovl_sz   = (size_t)N * 48 * 2 > (size_t)E * 4 ? (size_t)N * 48 * 2
                                                          : (size_t)E * 4;
    char*   ovl      = alloc(ovl_sz);
    int*    ebuf     = (int*)ovl;
    __half* h1p      = (__half*)ovl;
    __half* r1h      = (__half*)alloc((size_t)N * 48 * 2);
    __half* h2p      = h1p;  // h1p dead after k_agg1

    // cooperative build: 196 blocks (<=256 CUs, co-resident)
    const int* ei = ei_c;
    void* bargs[] = {(void*)&ei, (void*)&E, (void*)&Hw, (void*)&NBK,
                     (void*)&nTiles, (void*)&btot, (void*)&bstart, (void*)&ebuf,
                     (void*)&csr, (void*)&rowstart, (void*)&dinv, (void*)&N};
    hipLaunchCooperativeKernel((void*)k_build, dim3(nTiles), dim3(256),
                               bargs, 0, stream);

    hipLaunchKernelGGL(k_gemm1, dim3((N + 63) / 64), dim3(256), 0, stream,
                       x, W1, dinv, h1p, N);
    hipLaunchKernelGGL(k_agg1, dim3((N + 3) / 4), dim3(256), 0, stream,
                       h1p, csr, rowstart, dinv, b1, r1h, N);
    hipLaunchKernelGGL(k_gemm2, dim3((N * 4 + 255) / 256), dim3(256), 0, stream,
                       r1h, W2, dinv, h2p, N);
    hipLaunchKernelGGL(k_agg2, dim3((N + 7) / 8), dim3(256), 0, stream,
                       h2p, csr, rowstart, dinv, b2, out, N);
}

// Round 16
// 134.387 us; speedup vs baseline: 1.7902x; 1.7902x over previous
//
#include <hip/hip_runtime.h>
#include <hip/hip_bf16.h>
#include <hip/hip_fp16.h>

// GCN 2-layer: h1 = relu(Ahat (x@W1) + b1); out = softmax(relu(Ahat (h1@W2) + b2))
// Ahat = D^-1/2 (A + I) D^-1/2.
// dinv[src] folded into GEMM epilogues (h' = dinv*h, fp16); aggregation is a
// register gather + shfl reduce over interleaved 96B fp16 rows — round-11
// structure, best measured (47.6us, ~90% of the 2.6TB/s random-fetch ceiling;
// fetch-bound, rate invariant across VALUBusy 29-57%).
// Rejected by measurement: LDS-atomic scatter (10x), L2-chunking (4.7x),
// global-atomic deg (8x), fixed-8 unroll (1.6x), 128B-pad+fused-gemm2 (1.5x),
// cooperative fused build (4.6x — 196-block grid pins occupancy at 8.6%).
// CSR build: 5-kernel bucketed counting sort, LDS counting, int4 streams.

#define TILE 8192  // edges per histogram/scatter workgroup (196 blocks)

typedef _Float16 half8 __attribute__((ext_vector_type(8)));
typedef float floatx4 __attribute__((ext_vector_type(4)));

// per-tile bucket histogram -> Hw[tile][nbuck]   (bucket = dst>>8)
__global__ __launch_bounds__(256) void k_bhist(const int* __restrict__ dst, int E,
                                               int* __restrict__ Hw, int nbuck) {
    __shared__ int h[512];
    int t = threadIdx.x;
    for (int i = t; i < nbuck; i += 256) h[i] = 0;
    __syncthreads();
    int base = blockIdx.x * TILE;
#pragma unroll
    for (int r = 0; r < TILE / 1024; ++r) {   // int4 per thread
        int e = base + (r * 256 + t) * 4;
        if (e + 3 < E) {
            int4 d4 = *(const int4*)(dst + e);
            atomicAdd(&h[d4.x >> 8], 1);
            atomicAdd(&h[d4.y >> 8], 1);
            atomicAdd(&h[d4.z >> 8], 1);
            atomicAdd(&h[d4.w >> 8], 1);
        } else {
            for (int k = 0; k < 4; ++k)
                if (e + k < E) atomicAdd(&h[dst[e + k] >> 8], 1);
        }
    }
    __syncthreads();
    for (int i = t; i < nbuck; i += 256) Hw[blockIdx.x * nbuck + i] = h[i];
}

// one wave per bucket: column sum of Hw -> btot[b]
__global__ __launch_bounds__(256) void k_bsum(const int* __restrict__ Hw, int nTiles,
                                              int nbuck, int* __restrict__ btot) {
    int wid = (blockIdx.x * 256 + threadIdx.x) >> 6;
    int lane = threadIdx.x & 63;
    if (wid >= nbuck) return;
    int sum = 0;
    for (int tt = lane; tt < nTiles; tt += 64) sum += Hw[tt * nbuck + wid];
#pragma unroll
    for (int off = 32; off; off >>= 1) sum += __shfl_down(sum, off);
    if (lane == 0) btot[wid] = sum;
}

// one wave per bucket: compute own exclusive prefix of btot (-> bstart) and
// convert Hw column to absolute per-(tile,bucket) offsets. (fused bucket scan)
__global__ __launch_bounds__(256) void k_boff(int* __restrict__ Hw, int nTiles,
                                              int nbuck, const int* __restrict__ btot,
                                              int* __restrict__ bstart) {
    int wid = (blockIdx.x * 256 + threadIdx.x) >> 6;
    int lane = threadIdx.x & 63;
    if (wid >= nbuck) return;
    int ps = 0;
    for (int j = lane; j < wid; j += 64) ps += btot[j];
#pragma unroll
    for (int off = 32; off; off >>= 1) ps += __shfl_down(ps, off);
    int prefix = __shfl(ps, 0);
    if (lane == 0) {
        bstart[wid] = prefix;
        if (wid == nbuck - 1) bstart[nbuck] = prefix + btot[wid];
    }
    int running = prefix;
    for (int chunk = 0; chunk < nTiles; chunk += 64) {
        int tt = chunk + lane;
        int v = (tt < nTiles) ? Hw[tt * nbuck + wid] : 0;
        int incl = v;
#pragma unroll
        for (int off = 1; off < 64; off <<= 1) {
            int u = __shfl_up(incl, off);
            if (lane >= off) incl += u;
        }
        if (tt < nTiles) Hw[tt * nbuck + wid] = running + (incl - v);
        running += __shfl(incl, 63);
    }
}

// scatter edges bucket-grouped; packed entry = src | (dst&255)<<17  (src<2^17)
__global__ __launch_bounds__(256) void k_bscatter(const int* __restrict__ ei, int E,
                                                  const int* __restrict__ Hw, int nbuck,
                                                  int* __restrict__ ebuf) {
    __shared__ int cur[512];
    int t = threadIdx.x;
    for (int i = t; i < nbuck; i += 256) cur[i] = Hw[blockIdx.x * nbuck + i];
    __syncthreads();
    int base = blockIdx.x * TILE;
    bool al = (E & 3) == 0;  // dst stream ei+E alignment for int4
#pragma unroll
    for (int r = 0; r < TILE / 1024; ++r) {
        int e = base + (r * 256 + t) * 4;
        if (al && e + 3 < E) {
            int4 s4 = *(const int4*)(ei + e);
            int4 d4 = *(const int4*)(ei + E + e);
            int p0 = atomicAdd(&cur[d4.x >> 8], 1);
            ebuf[p0] = s4.x | ((d4.x & 255) << 17);
            int p1 = atomicAdd(&cur[d4.y >> 8], 1);
            ebuf[p1] = s4.y | ((d4.y & 255) << 17);
            int p2 = atomicAdd(&cur[d4.z >> 8], 1);
            ebuf[p2] = s4.z | ((d4.z & 255) << 17);
            int p3 = atomicAdd(&cur[d4.w >> 8], 1);
            ebuf[p3] = s4.w | ((d4.w & 255) << 17);
        } else {
            for (int k = 0; k < 4; ++k) {
                int ek = e + k;
                if (ek < E) {
                    int s = ei[ek];
                    int d = ei[E + ek];
                    int pos = atomicAdd(&cur[d >> 8], 1);
                    ebuf[pos] = s | ((d & 255) << 17);
                }
            }
        }
    }
}

// one WG per bucket (256 nodes): LDS count -> scan -> rowstart/dinv + csr fill
// (int4-vectorized ebuf reads; scalar head/tail for alignment)
__global__ __launch_bounds__(256) void k_csrfill(const int* __restrict__ ebuf,
                                                 const int* __restrict__ bstart,
                                                 int* __restrict__ csr,
                                                 int* __restrict__ rowstart,
                                                 float* __restrict__ dinv, int N) {
    __shared__ int lcnt[256];
    __shared__ int lscan[256];
    __shared__ int lcur[256];
    int t = threadIdx.x;
    int nodebase = blockIdx.x << 8;
    int segs = bstart[blockIdx.x];
    int sege = bstart[blockIdx.x + 1];
    int vstart = (segs + 3) & ~3;
    if (vstart > sege) vstart = sege;
    int vend = sege & ~3;
    if (vend < vstart) vend = vstart;
    lcnt[t] = 0;
    __syncthreads();
    // pass 1: count
    for (int i = segs + t; i < vstart; i += 256)
        atomicAdd(&lcnt[((unsigned)ebuf[i]) >> 17], 1);
    for (int i = vstart + t * 4; i < vend; i += 1024) {
        int4 p4 = *(const int4*)(ebuf + i);
        atomicAdd(&lcnt[((unsigned)p4.x) >> 17], 1);
        atomicAdd(&lcnt[((unsigned)p4.y) >> 17], 1);
        atomicAdd(&lcnt[((unsigned)p4.z) >> 17], 1);
        atomicAdd(&lcnt[((unsigned)p4.w) >> 17], 1);
    }
    for (int i = vend + t; i < sege; i += 256)
        atomicAdd(&lcnt[((unsigned)ebuf[i]) >> 17], 1);
    __syncthreads();
    int v = lcnt[t];
    lscan[t] = v;
    __syncthreads();
    for (int off = 1; off < 256; off <<= 1) {
        int tmp = (t >= off) ? lscan[t - off] : 0;
        __syncthreads();
        lscan[t] += tmp;
        __syncthreads();
    }
    int excl = lscan[t] - v;
    int node = nodebase + t;
    int rs = segs + excl;
    if (node < N) {
        rowstart[node] = rs;
        dinv[node] = rsqrtf((float)(v + 1));  // +1 self loop
        if (node == N - 1) rowstart[N] = rs + v;  // sentinel
    }
    lcur[t] = rs;
    __syncthreads();
    // pass 2: fill
    for (int i = segs + t; i < vstart; i += 256) {
        int pk = ebuf[i];
        int pos = atomicAdd(&lcur[((unsigned)pk) >> 17], 1);
        csr[pos] = pk & 0x1FFFF;
    }
    for (int i = vstart + t * 4; i < vend; i += 1024) {
        int4 p4 = *(const int4*)(ebuf + i);
        int pos0 = atomicAdd(&lcur[((unsigned)p4.x) >> 17], 1);
        csr[pos0] = p4.x & 0x1FFFF;
        int pos1 = atomicAdd(&lcur[((unsigned)p4.y) >> 17], 1);
        csr[pos1] = p4.y & 0x1FFFF;
        int pos2 = atomicAdd(&lcur[((unsigned)p4.z) >> 17], 1);
        csr[pos2] = p4.z & 0x1FFFF;
        int pos3 = atomicAdd(&lcur[((unsigned)p4.w) >> 17], 1);
        csr[pos3] = p4.w & 0x1FFFF;
    }
    for (int i = vend + t; i < sege; i += 256) {
        int pk = ebuf[i];
        int pos = atomicAdd(&lcur[((unsigned)pk) >> 17], 1);
        csr[pos] = pk & 0x1FFFF;
    }
}

// h1p[N][48] = fp16( dinv[r] * (x[N][128] @ W1[128][48]) ) via MFMA 16x16x32 f16.
__global__ __launch_bounds__(256) void k_gemm1(const float* __restrict__ x,
                                               const float* __restrict__ W1,
                                               const float* __restrict__ dinv,
                                               __half* __restrict__ h1p, int N) {
    __shared__ _Float16 wt[48 * 136];
    int t = threadIdx.x;
    for (int i = t; i < 128 * 48; i += 256) {
        int k = i / 48, c = i % 48;
        wt[c * 136 + k] = (_Float16)W1[i];
    }
    __syncthreads();

    int wave = t >> 6, lane = t & 63;
    int g = lane >> 4;
    int rtile = blockIdx.x * 64 + wave * 16;
    int rowA = rtile + (lane & 15);
    const float* xrow = x + (size_t)(rowA < N ? rowA : N - 1) * 128;
    int c0 = lane & 15;

    floatx4 acc[3];
#pragma unroll
    for (int nt = 0; nt < 3; ++nt)
#pragma unroll
        for (int q = 0; q < 4; ++q) acc[nt][q] = 0.f;

#pragma unroll
    for (int kc = 0; kc < 4; ++kc) {
        int k0 = kc * 32 + g * 8;
        float4 a0 = *(const float4*)(xrow + k0);
        float4 a1 = *(const float4*)(xrow + k0 + 4);
        half8 a;
        a[0] = (_Float16)a0.x; a[1] = (_Float16)a0.y;
        a[2] = (_Float16)a0.z; a[3] = (_Float16)a0.w;
        a[4] = (_Float16)a1.x; a[5] = (_Float16)a1.y;
        a[6] = (_Float16)a1.z; a[7] = (_Float16)a1.w;
#pragma unroll
        for (int nt = 0; nt < 3; ++nt) {
            half8 b = *(const half8*)(&wt[(nt * 16 + c0) * 136 + k0]);
            acc[nt] = __builtin_amdgcn_mfma_f32_16x16x32_f16(a, b, acc[nt], 0, 0, 0);
        }
    }

    int rbase = rtile + g * 4;
#pragma unroll
    for (int j = 0; j < 4; ++j) {
        int r = rbase + j;
        if (r < N) {
            float dr = dinv[r];
#pragma unroll
            for (int nt = 0; nt < 3; ++nt)
                h1p[(size_t)r * 48 + nt * 16 + c0] = __float2half(acc[nt][j] * dr);
        }
    }
}

// layer-1 aggregation (round-11 structure, best measured): wave per node;
// 8 edge-groups x (6 lanes x float4) over 96B rows; degree-adaptive loop;
// shfl-xor fold; epilogue self + bias + relu, writes r1 fp16.
__global__ __launch_bounds__(256) void k_agg1(const __half* __restrict__ h1p,
                                              const int* __restrict__ csr,
                                              const int* __restrict__ rowstart,
                                              const float* __restrict__ dinv,
                                              const float* __restrict__ b1,
                                              __half* __restrict__ r1h, int N) {
    int wave = threadIdx.x >> 6;
    int lane = threadIdx.x & 63;
    int v = blockIdx.x * 4 + wave;
    if (v >= N) return;
    int grp = lane >> 3;  // edge group 0..7
    int sub = lane & 7;   // subs 0..5 carry features sub*8..sub*8+7

    int start = rowstart[v];
    int d = rowstart[v + 1] - start;
    float dv = dinv[v];
    const int* cs = csr + start;
    const char* h1b = (const char*)h1p;

    float acc[8] = {0.f, 0.f, 0.f, 0.f, 0.f, 0.f, 0.f, 0.f};

    for (int base = 0; base < d; base += 64) {
        int sreg = (base + lane < d) ? cs[base + lane] : 0;
        int nb = min(64, d - base);
        for (int j = 0; j < 8 && j * 8 < nb; ++j) {
            int s = __shfl(sreg, j * 8 + grp);
            if (j * 8 + grp < nb && sub < 6) {
                float4 rv = *(const float4*)(h1b + (size_t)s * 96 + sub * 16);
                const __half2* hp = (const __half2*)&rv;
#pragma unroll
                for (int q = 0; q < 4; ++q) {
                    float2 f = __half22float2(hp[q]);
                    acc[q * 2] += f.x;
                    acc[q * 2 + 1] += f.y;
                }
            }
        }
    }
    // fold the 8 edge groups (idle sub-lanes hold zeros)
#pragma unroll
    for (int i = 0; i < 8; ++i) {
        acc[i] += __shfl_xor(acc[i], 8);
        acc[i] += __shfl_xor(acc[i], 16);
        acc[i] += __shfl_xor(acc[i], 32);
    }
    if (grp == 0 && sub < 6) {
        float4 sv = *(const float4*)(h1b + (size_t)v * 96 + sub * 16);
        const __half2* hp = (const __half2*)&sv;
        __half2 ob[4];
#pragma unroll
        for (int q = 0; q < 4; ++q) {
            float2 sf = __half22float2(hp[q]);
            int fi = sub * 8 + q * 2;
            float o0 = fmaxf(dv * (acc[q * 2] + sf.x) + b1[fi], 0.f);
            float o1 = fmaxf(dv * (acc[q * 2 + 1] + sf.y) + b1[fi + 1], 0.f);
            ob[q] = __floats2half2_rn(o0, o1);
        }
        *(float4*)((char*)r1h + (size_t)v * 96 + sub * 16) = *(const float4*)ob;
    }
}

// h2p[N][16] = fp16( dinv[row] * (r1h[N][48] @ W2[48][16]) ), r1h fp16
__global__ __launch_bounds__(256) void k_gemm2(const __half* __restrict__ r1h,
                                               const float* __restrict__ W2,
                                               const float* __restrict__ dinv,
                                               __half* __restrict__ h2p, int N) {
    __shared__ float w2s[48 * 16];
    int t = threadIdx.x;
    for (int i = t; i < 768; i += 256) w2s[i] = W2[i];
    __syncthreads();
    int flat = blockIdx.x * 256 + t;
    int row = flat >> 2;
    int cg = (flat & 3) * 4;
    if (row >= N) return;
    float4 acc = make_float4(0.f, 0.f, 0.f, 0.f);
    const __half2* xr = (const __half2*)((const char*)r1h + (size_t)row * 96);
#pragma unroll 4
    for (int kk = 0; kk < 24; ++kk) {
        float2 a = __half22float2(xr[kk]);
        float4 b0 = *(const float4*)(w2s + (2 * kk) * 16 + cg);
        float4 b1v = *(const float4*)(w2s + (2 * kk + 1) * 16 + cg);
        acc.x += a.x * b0.x + a.y * b1v.x;
        acc.y += a.x * b0.y + a.y * b1v.y;
        acc.z += a.x * b0.z + a.y * b1v.z;
        acc.w += a.x * b0.w + a.y * b1v.w;
    }
    float dr = dinv[row];
    __half2 h01 = __floats2half2_rn(acc.x * dr, acc.y * dr);
    __half2 h23 = __floats2half2_rn(acc.z * dr, acc.w * dr);
    __half* dst = h2p + (size_t)row * 16 + cg;
    *(__half2*)(dst) = h01;
    *(__half2*)(dst + 2) = h23;
}

// layer-2 aggregation: 2 nodes/wave; per half-wave 16 edge-groups x
// (2 lanes x float4) = 16 edges per load instruction. Softmax in sub-lanes.
__global__ __launch_bounds__(256) void k_agg2(const __half* __restrict__ h2p,
                                              const int* __restrict__ csr,
                                              const int* __restrict__ rowstart,
                                              const float* __restrict__ dinv,
                                              const float* __restrict__ b2,
                                              float* __restrict__ out, int N) {
    int tid = threadIdx.x;
    int lane = tid & 63;
    int hf = lane >> 5;
    int l32 = lane & 31;
    int grp = l32 >> 1;
    int sub = lane & 1;
    int v = (blockIdx.x * 4 + (tid >> 6)) * 2 + hf;
    if (v >= N) return;

    int start = rowstart[v];
    int d = rowstart[v + 1] - start;
    float dv = dinv[v];
    const int* cs = csr + start;
    const char* h2b = (const char*)h2p;

    float acc[8] = {0.f, 0.f, 0.f, 0.f, 0.f, 0.f, 0.f, 0.f};

    for (int base = 0; base < d; base += 32) {
        int sreg = (base + l32 < d) ? cs[base + l32] : 0;
        int nb = min(32, d - base);
        for (int j = 0; j < 2 && j * 16 < nb; ++j) {
            int e = j * 16 + grp;
            int s = __shfl(sreg, (hf << 5) + e);
            if (e < nb) {
                float4 rv = *(const float4*)(h2b + (size_t)s * 32 + sub * 16);
                const __half2* hp = (const __half2*)&rv;
#pragma unroll
                for (int q = 0; q < 4; ++q) {
                    float2 f = __half22float2(hp[q]);
                    acc[q * 2] += f.x;
                    acc[q * 2 + 1] += f.y;
                }
            }
        }
    }
#pragma unroll
    for (int i = 0; i < 8; ++i) {
        acc[i] += __shfl_xor(acc[i], 2);
        acc[i] += __shfl_xor(acc[i], 4);
        acc[i] += __shfl_xor(acc[i], 8);
        acc[i] += __shfl_xor(acc[i], 16);
    }
    if (grp == 0) {
        float4 sv = *(const float4*)(h2b + (size_t)v * 32 + sub * 16);
        const __half2* hp = (const __half2*)&sv;
        float z[8];
#pragma unroll
        for (int q = 0; q < 4; ++q) {
            float2 f = __half22float2(hp[q]);
            z[q * 2]     = fmaxf(dv * (acc[q * 2] + f.x) + b2[sub * 8 + q * 2], 0.f);
            z[q * 2 + 1] = fmaxf(dv * (acc[q * 2 + 1] + f.y) + b2[sub * 8 + q * 2 + 1], 0.f);
        }
        float m8 = z[0];
#pragma unroll
        for (int i = 1; i < 8; ++i) m8 = fmaxf(m8, z[i]);
        float m = fmaxf(m8, __shfl_xor(m8, 1));
        float p[8];
        float s8 = 0.f;
#pragma unroll
        for (int i = 0; i < 8; ++i) { p[i] = __expf(z[i] - m); s8 += p[i]; }
        float inv = 1.f / (s8 + __shfl_xor(s8, 1));
        float4* dst = (float4*)(out + (size_t)v * 16 + sub * 8);
        dst[0] = make_float4(p[0] * inv, p[1] * inv, p[2] * inv, p[3] * inv);
        dst[1] = make_float4(p[4] * inv, p[5] * inv, p[6] * inv, p[7] * inv);
    }
}

extern "C" void kernel_launch(void* const* d_in, const int* in_sizes, int n_in,
                              void* d_out, int out_size, void* d_ws, size_t ws_size,
                              hipStream_t stream) {
    const float* x  = (const float*)d_in[0];
    const int*   ei = (const int*)d_in[1];
    const float* W1 = (const float*)d_in[2];
    const float* b1 = (const float*)d_in[3];
    const float* W2 = (const float*)d_in[4];
    const float* b2 = (const float*)d_in[5];
    float* out = (float*)d_out;

    int N = in_sizes[0] / 128;
    int E = in_sizes[1] / 2;
    int NBK = (N + 255) >> 8;
    int nTiles = (E + TILE - 1) / TILE;

    char* p = (char*)d_ws;
    auto alloc = [&](size_t bytes) -> char* {
        char* q = p;
        p += (bytes + 255) & ~(size_t)255;
        return q;
    };
    int*    rowstart = (int*)alloc((size_t)(N + 1) * 4);   // +1 sentinel
    float*  dinv     = (float*)alloc((size_t)N * 4);
    int*    btot     = (int*)alloc((size_t)NBK * 4);
    int*    bstart   = (int*)alloc((size_t)(NBK + 1) * 4);
    int*    Hw       = (int*)alloc((size_t)nTiles * NBK * 4);
    int*    csr      = (int*)alloc((size_t)E * 4);
    // ebuf (E*4) dead after k_csrfill; h1p (N*48*2) overlays it; h2p after agg1.
    size_t  ovl_sz   = (size_t)N * 48 * 2 > (size_t)E * 4 ? (size_t)N * 48 * 2
                                                          : (size_t)E * 4;
    char*   ovl      = alloc(ovl_sz);
    int*    ebuf     = (int*)ovl;
    __half* h1p      = (__half*)ovl;
    __half* r1h      = (__half*)alloc((size_t)N * 48 * 2);
    __half* h2p      = h1p;  // h1p dead after k_agg1

    int wgBuck = (NBK + 3) / 4;  // 4 waves per 256-thread block

    hipLaunchKernelGGL(k_bhist, dim3(nTiles), dim3(256), 0, stream, ei + E, E, Hw, NBK);
    hipLaunchKernelGGL(k_bsum, dim3(wgBuck), dim3(256), 0, stream, Hw, nTiles, NBK, btot);
    hipLaunchKernelGGL(k_boff, dim3(wgBuck), dim3(256), 0, stream, Hw, nTiles, NBK,
                       btot, bstart);
    hipLaunchKernelGGL(k_bscatter, dim3(nTiles), dim3(256), 0, stream, ei, E, Hw, NBK, ebuf);
    hipLaunchKernelGGL(k_csrfill, dim3(NBK), dim3(256), 0, stream,
                       ebuf, bstart, csr, rowstart, dinv, N);
    hipLaunchKernelGGL(k_gemm1, dim3((N + 63) / 64), dim3(256), 0, stream,
                       x, W1, dinv, h1p, N);
    hipLaunchKernelGGL(k_agg1, dim3((N + 3) / 4), dim3(256), 0, stream,
                       h1p, csr, rowstart, dinv, b1, r1h, N);
    hipLaunchKernelGGL(k_gemm2, dim3((N * 4 + 255) / 256), dim3(256), 0, stream,
                       r1h, W2, dinv, h2p, N);
    hipLaunchKernelGGL(k_agg2, dim3((N + 7) / 8), dim3(256), 0, stream,
                       h2p, csr, rowstart, dinv, b2, out, N);
}